// Round 1
// baseline (1241.521 us; speedup 1.0000x reference)
//
#include <hip/hip_runtime.h>

#define T_TOKENS 8192
#define E_NUM    8
#define R_K      128
#define O_OUT    4096
#define EO       (E_NUM * O_OUT)      // 32768, out row stride
#define XLD      (E_NUM * R_K)        // 1024, x row stride

#define LDS_STRIDE 136                // 128 + 8 bf16 pad (16B) -> b128 reads at bank floor

typedef __attribute__((ext_vector_type(8))) short  short8;   // 8 bf16 = 4 VGPRs (MFMA A/B frag)
typedef __attribute__((ext_vector_type(4))) short  s16x4;    // 8 B LDS write
typedef __attribute__((ext_vector_type(4))) float  f32x4;    // MFMA C/D frag

__device__ __forceinline__ short f2bf(float f) {
    // round-to-nearest-even fp32 -> bf16 (inputs are well-behaved normals)
    unsigned u = __float_as_uint(f);
    u += 0x7FFFu + ((u >> 16) & 1u);
    return (short)(u >> 16);
}

__global__ __launch_bounds__(256) void moe_lora_b_kernel(
    const float* __restrict__ x,   // [T, E*R]
    const float* __restrict__ W,   // [E, O, R]
    float* __restrict__ out)       // [T, E, O]
{
    __shared__ short As[128 * LDS_STRIDE];  // [token-row][k]  bf16
    __shared__ short Bs[128 * LDS_STRIDE];  // [out-row][k]    bf16

    const int tid = threadIdx.x;
    const int bid = blockIdx.x;
    const int e   = bid & 7;          // expert -> XCD swizzle (round-robin dispatch)
    const int t2  = bid >> 3;
    const int ot  = t2 & 31;          // 32 O-tiles
    const int tt  = t2 >> 5;          // 64 T-tiles
    const int t0  = tt << 7;
    const int o0  = ot << 7;

    // ---- stage A (x slice) and B (W_e rows) fp32 -> bf16 into LDS ----
    {
        const float* __restrict__ xa = x + (size_t)t0 * XLD + e * R_K;
        const float* __restrict__ wb = W + ((size_t)e * O_OUT + o0) * R_K;
        #pragma unroll
        for (int it = 0; it < 16; ++it) {
            int f   = (it * 256 + tid) << 2;   // flat element idx, x4 vectorized
            int row = f >> 7;                  // /128
            int col = f & 127;
            float4 va = *(const float4*)(xa + (size_t)row * XLD + col);
            float4 vb = *(const float4*)(wb + (size_t)row * R_K + col);
            s16x4 sa, sb;
            sa.x = f2bf(va.x); sa.y = f2bf(va.y); sa.z = f2bf(va.z); sa.w = f2bf(va.w);
            sb.x = f2bf(vb.x); sb.y = f2bf(vb.y); sb.z = f2bf(vb.z); sb.w = f2bf(vb.w);
            *(s16x4*)&As[row * LDS_STRIDE + col] = sa;   // 2-way bank alias: free
            *(s16x4*)&Bs[row * LDS_STRIDE + col] = sb;
        }
    }
    __syncthreads();

    // ---- compute: 4 waves in 2x2, each wave 64x64 as 4x4 of 16x16x32 MFMA ----
    const int lane = tid & 63;
    const int wave = tid >> 6;
    const int wr   = (wave >> 1) << 6;   // wave row offset in tile
    const int wc   = (wave & 1) << 6;    // wave col offset in tile
    const int m    = lane & 15;
    const int quad = lane >> 4;          // 0..3

    f32x4 acc[4][4] = {};

    #pragma unroll
    for (int kk = 0; kk < 4; ++kk) {     // K = 128 = 4 x 32
        short8 a[4], b[4];
        const int kcol = kk * 32 + quad * 8;
        #pragma unroll
        for (int i = 0; i < 4; ++i) {
            a[i] = *(const short8*)&As[(wr + i * 16 + m) * LDS_STRIDE + kcol];
            b[i] = *(const short8*)&Bs[(wc + i * 16 + m) * LDS_STRIDE + kcol];
        }
        #pragma unroll
        for (int i = 0; i < 4; ++i)
            #pragma unroll
            for (int j = 0; j < 4; ++j)
                acc[i][j] = __builtin_amdgcn_mfma_f32_16x16x32_bf16(a[i], b[j], acc[i][j], 0, 0, 0);
    }

    // ---- epilogue: C/D layout col=lane&15, row=quad*4+reg ----
    #pragma unroll
    for (int i = 0; i < 4; ++i) {
        const int row_base = t0 + wr + i * 16 + quad * 4;
        #pragma unroll
        for (int j = 0; j < 4; ++j) {
            const int col = o0 + wc + j * 16 + m;
            size_t base = (size_t)row_base * EO + (size_t)e * O_OUT + col;
            #pragma unroll
            for (int r = 0; r < 4; ++r)
                out[base + (size_t)r * EO] = acc[i][j][r];
        }
    }
}

extern "C" void kernel_launch(void* const* d_in, const int* in_sizes, int n_in,
                              void* d_out, int out_size, void* d_ws, size_t ws_size,
                              hipStream_t stream) {
    const float* x = (const float*)d_in[0];   // [8192, 1024] fp32
    const float* W = (const float*)d_in[1];   // [8, 4096, 128] fp32
    float* out = (float*)d_out;               // [8192, 8, 4096] fp32

    const int n_blocks = (T_TOKENS / 128) * (O_OUT / 128) * E_NUM;  // 16384
    moe_lora_b_kernel<<<n_blocks, 256, 0, stream>>>(x, W, out);
}